// Round 3
// baseline (653.740 us; speedup 1.0000x reference)
//
#include <hip/hip_runtime.h>

// MeanAggregator: out[b,:] = mean over {neighbours[b,0..9], nodes[b]} of features[idx,:]
// B=100000, K=10, N=1000000, D=128. Pure memory-bound random gather.
//
// Layout: 32 lanes per node, float4 (ext_vector) per lane -> 32*16B = 512B = one
// full feature row; each wave-level VMEM instruction moves 1KB (two nodes).
// Persistent grid-stride with software-pipelined index prefetch: the next
// node's 11 index loads are issued while the current node's 11 row loads are
// in flight, breaking the index->row latency chain. Nontemporal stores keep
// the 51MB output from polluting L3 (features dedup lives there).

#define KNEIGH 10
#define DDIM 128

typedef float v4f __attribute__((ext_vector_type(4)));

__global__ __launch_bounds__(256) void MeanAggregator_36386962932386_kernel(
    const int* __restrict__ nodes,
    const int* __restrict__ neighbours,
    const float* __restrict__ features,
    float* __restrict__ out,
    int B)
{
    const int g = threadIdx.x >> 5;     // node group within block (0..7)
    const int c = threadIdx.x & 31;     // float4 column within feature row
    const int step = gridDim.x * 8;

    int node = blockIdx.x * 8 + g;
    if (node >= B) return;

    // Indices for the first node.
    int idx[KNEIGH + 1];
    {
        const long long nb = (long long)node * KNEIGH;
#pragma unroll
        for (int j = 0; j < KNEIGH; ++j) idx[j] = neighbours[nb + j];
        idx[KNEIGH] = nodes[node];
    }

    while (true) {
        const int next = node + step;

        // Issue all 11 independent 512B row loads for the current node.
        v4f v[KNEIGH + 1];
#pragma unroll
        for (int j = 0; j <= KNEIGH; ++j) {
            v[j] = ((const v4f*)(features + (long long)idx[j] * DDIM))[c];
        }

        // Prefetch next node's indices while row loads are in flight.
        int nidx[KNEIGH + 1];
        if (next < B) {
            const long long nb2 = (long long)next * KNEIGH;
#pragma unroll
            for (int j = 0; j < KNEIGH; ++j) nidx[j] = neighbours[nb2 + j];
            nidx[KNEIGH] = nodes[next];
        }

        // Reduce + scale.
        v4f acc = v[0];
#pragma unroll
        for (int j = 1; j <= KNEIGH; ++j) acc += v[j];
        acc *= (1.0f / (float)(KNEIGH + 1));

        // Nontemporal store: output is write-once, keep it out of L3.
        __builtin_nontemporal_store(acc, (v4f*)(out + (long long)node * DDIM) + c);

        if (next >= B) break;
        node = next;
#pragma unroll
        for (int j = 0; j <= KNEIGH; ++j) idx[j] = nidx[j];
    }
}

extern "C" void kernel_launch(void* const* d_in, const int* in_sizes, int n_in,
                              void* d_out, int out_size, void* d_ws, size_t ws_size,
                              hipStream_t stream)
{
    const int* nodes      = (const int*)d_in[0];
    const int* neighbours = (const int*)d_in[1];
    const float* features = (const float*)d_in[2];
    float* out            = (float*)d_out;

    const int B = in_sizes[0];           // 100000

    // Persistent-ish grid: 2048 blocks x 8 nodes/iter -> ~6 pipelined
    // iterations per 32-lane group; full chip residency (8 blocks/CU).
    int blocks = 2048;
    const int max_blocks = (B + 7) / 8;
    if (blocks > max_blocks) blocks = max_blocks;

    MeanAggregator_36386962932386_kernel<<<blocks, 256, 0, stream>>>(
        nodes, neighbours, features, out, B);
}